// Round 2
// baseline (21.519 us; speedup 1.0000x reference)
//
#include <hip/hip_runtime.h>
#include <hip/hip_bf16.h>

#define H  128
#define W  128
#define HO 127
#define WO 127

// Tiny prep kernel: sincos of the 8 weight half-angles into d_ws[16].
__global__ void prep_weights(const float* __restrict__ wts, float* __restrict__ ws) {
    int t = threadIdx.x;
    if (t < 8) {
        float s, c;
        __sincosf(0.5f * wts[t], &s, &c);
        ws[t]     = c;
        ws[8 + t] = s;
    }
}

// Each thread computes 4 consecutive output pixels (one j-group) of one row.
// Block: 256 threads = 32 j-groups x 8 rows. Grid: (1, 16, B).
__global__ __launch_bounds__(256) void quonv4(
    const float* __restrict__ img,   // [B,128,128,1]
    const float* __restrict__ wcs,   // [16] = cos(h0..h7), sin(h0..h7)
    float* __restrict__ out)         // [B,127,127,4]
{
    const int t  = threadIdx.x;
    const int jg = t & 31;
    const int ty = t >> 5;
    const int i  = blockIdx.y * 8 + ty;
    const int b  = blockIdx.z;
    if (i >= HO) return;
    const int j0 = jg * 4;

    // Weight sincos: uniform address -> scalar loads (broadcast).
    float wc[8], ws_[8];
#pragma unroll
    for (int k = 0; k < 8; ++k) { wc[k] = wcs[k]; ws_[k] = wcs[8 + k]; }

    // ---- load 5 pixels from each of 2 rows (float4 + guarded scalar) ----
    const float* r0p = img + ((size_t)b * H + i) * W + j0;
    const float* r1p = r0p + W;
    float4 q0 = *reinterpret_cast<const float4*>(r0p);
    float4 q1 = *reinterpret_cast<const float4*>(r1p);
    float r0[5] = {q0.x, q0.y, q0.z, q0.w, 0.f};
    float r1[5] = {q1.x, q1.y, q1.z, q1.w, 0.f};
    if (j0 + 4 < W) { r0[4] = r0p[4]; r1[4] = r1p[4]; }

    // ---- sincos of pi*p/2 per pixel (shared across adjacent patches) ----
    float c0[5], s0[5], c1[5], s1[5];
#pragma unroll
    for (int k = 0; k < 5; ++k) {
        __sincosf(1.57079632679489662f * r0[k], &s0[k], &c0[k]);
        __sincosf(1.57079632679489662f * r1[k], &s1[k], &c1[k]);
    }

    // ---- embedding product states for 4 patches ----
    // wire0 = r0[k] (bit3), wire1 = r0[k+1] (bit2), wire2 = r1[k] (bit1), wire3 = r1[k+1] (bit0)
    float st[4][16];
#pragma unroll
    for (int k = 0; k < 4; ++k) {
        float t01[4], t23[4];
        t01[0] = c0[k] * c0[k + 1]; t01[1] = c0[k] * s0[k + 1];
        t01[2] = s0[k] * c0[k + 1]; t01[3] = s0[k] * s0[k + 1];
        t23[0] = c1[k] * c1[k + 1]; t23[1] = c1[k] * s1[k + 1];
        t23[2] = s1[k] * c1[k + 1]; t23[3] = s1[k] * s1[k + 1];
#pragma unroll
        for (int x = 0; x < 16; ++x)
            st[k][x] = t01[x >> 2] * t23[x & 3];
    }

    // ---- 2 layers: RY(weights) per wire, then CNOT ring (4 patches interleaved) ----
#pragma unroll
    for (int l = 0; l < 2; ++l) {
#pragma unroll
        for (int w = 0; w < 4; ++w) {
            const float cc = wc[l * 4 + w];
            const float ss = ws_[l * 4 + w];
            const int m = 8 >> w;
#pragma unroll
            for (int x = 0; x < 16; ++x) {
                if (!(x & m)) {
#pragma unroll
                    for (int k = 0; k < 4; ++k) {
                        const float a  = st[k][x];
                        const float bb = st[k][x | m];
                        st[k][x]     = cc * a - ss * bb;
                        st[k][x | m] = ss * a + cc * bb;
                    }
                }
            }
        }
#pragma unroll
        for (int q = 0; q < 4; ++q) {
            const int mc = 8 >> q;
            const int mt = 8 >> ((q + 1) & 3);
#pragma unroll
            for (int x = 0; x < 16; ++x) {
                if ((x & mc) && !(x & mt)) {
#pragma unroll
                    for (int k = 0; k < 4; ++k) {
                        const float tmp = st[k][x];
                        st[k][x]      = st[k][x | mt];
                        st[k][x | mt] = tmp;
                    }
                }
            }
        }
    }

    // ---- expvals via shared Walsh trees; guarded coalesced float4 stores ----
    float* op = out + (((size_t)b * HO + i) * WO + j0) * 4;
#pragma unroll
    for (int k = 0; k < 4; ++k) {
        float pr[16];
#pragma unroll
        for (int x = 0; x < 16; ++x) pr[x] = st[k][x] * st[k][x];
        float a[8], bd[8];
#pragma unroll
        for (int x = 0; x < 8; ++x) {
            a[x]  = pr[2 * x] + pr[2 * x + 1];
            bd[x] = pr[2 * x] - pr[2 * x + 1];
        }
        const float e3 = ((bd[0] + bd[1]) + (bd[2] + bd[3])) + ((bd[4] + bd[5]) + (bd[6] + bd[7]));
        float c_[4], d_[4];
#pragma unroll
        for (int x = 0; x < 4; ++x) {
            c_[x] = a[2 * x] + a[2 * x + 1];
            d_[x] = a[2 * x] - a[2 * x + 1];
        }
        const float e2 = (d_[0] + d_[1]) + (d_[2] + d_[3]);
        const float e1 = (c_[0] - c_[1]) + (c_[2] - c_[3]);
        const float e0 = (c_[0] + c_[1]) - (c_[2] + c_[3]);
        if (j0 + k < WO)
            *reinterpret_cast<float4*>(op + 4 * k) = make_float4(e0, e1, e2, e3);
    }
}

extern "C" void kernel_launch(void* const* d_in, const int* in_sizes, int n_in,
                              void* d_out, int out_size, void* d_ws, size_t ws_size,
                              hipStream_t stream) {
    const float* img = (const float*)d_in[0];
    const float* wts = (const float*)d_in[1];
    float* out = (float*)d_out;
    float* ws  = (float*)d_ws;

    const int B = in_sizes[0] / (H * W);   // 64

    prep_weights<<<dim3(1), dim3(64), 0, stream>>>(wts, ws);

    dim3 grid(1, (HO + 7) / 8, B);         // (1, 16, 64)
    dim3 block(256, 1, 1);
    quonv4<<<grid, block, 0, stream>>>(img, ws, out);
}

// Round 3
// 16.804 us; speedup vs baseline: 1.2806x; 1.2806x over previous
//
#include <hip/hip_runtime.h>
#include <hip/hip_bf16.h>

#define H  128
#define W  128
#define HO 127
#define WO 127

// One patch per thread. Block 256 = 128 cols x 2 rows. Grid (1, 64, B).
// All sin/cos via raw v_sin_f32/v_cos_f32 (args pre-reduced, in revolutions).
__global__ __launch_bounds__(256) void quonv_kernel(
    const float* __restrict__ img,   // [B,128,128,1]
    const float* __restrict__ wts,   // [2,4] in [0, 2pi]
    float* __restrict__ out)         // [B,127,127,4]
{
    const int t  = threadIdx.x;
    const int j  = t & 127;
    const int ty = t >> 7;
    const int i  = blockIdx.y * 2 + ty;
    const int b  = blockIdx.z;
    if (i >= HO || j >= WO) return;

    // ---- weight half-angle sincos: theta/2 rad -> theta/(4pi) revolutions ----
    // wts reads are wave-uniform -> scalar loads; trans ops overlap VALU.
    float wc[8], ws_[8];
#pragma unroll
    for (int k = 0; k < 8; ++k) {
        const float a = wts[k] * 0.07957747154594767f;  // 1/(4*pi)
        wc[k]  = __builtin_amdgcn_cosf(a);
        ws_[k] = __builtin_amdgcn_sinf(a);
    }

    // ---- load 2x2 patch ----
    const float* r0p = img + ((size_t)b * H + i) * W + j;
    float p[4];
    p[0] = r0p[0];
    p[1] = r0p[1];
    p[2] = r0p[W];
    p[3] = r0p[W + 1];

    // ---- embedding sincos: pi*p/2 rad -> p/4 revolutions (p in [0,1]) ----
    float ec[4], es[4];
#pragma unroll
    for (int w = 0; w < 4; ++w) {
        const float a = p[w] * 0.25f;
        ec[w] = __builtin_amdgcn_cosf(a);
        es[w] = __builtin_amdgcn_sinf(a);
    }

    // ---- product state |psi> = (c0,s0) x (c1,s1) x (c2,s2) x (c3,s3) ----
    // bit of wire w is bit (3-w) of idx
    float t01[4], t23[4];
    t01[0] = ec[0] * ec[1]; t01[1] = ec[0] * es[1];
    t01[2] = es[0] * ec[1]; t01[3] = es[0] * es[1];
    t23[0] = ec[2] * ec[3]; t23[1] = ec[2] * es[3];
    t23[2] = es[2] * ec[3]; t23[3] = es[2] * es[3];

    float st[16];
#pragma unroll
    for (int x = 0; x < 16; ++x)
        st[x] = t01[x >> 2] * t23[x & 3];

    // ---- 2 entangling layers: RY(weights) per wire, then CNOT ring ----
#pragma unroll
    for (int l = 0; l < 2; ++l) {
#pragma unroll
        for (int w = 0; w < 4; ++w) {
            const float cc = wc[l * 4 + w];
            const float ss = ws_[l * 4 + w];
            const int m = 8 >> w;
#pragma unroll
            for (int x = 0; x < 16; ++x) {
                if (!(x & m)) {
                    const float a  = st[x];
                    const float bb = st[x | m];
                    const float f1 = ss * bb;
                    const float f2 = ss * a;
                    st[x]     = __builtin_fmaf(cc, a,  -f1);
                    st[x | m] = __builtin_fmaf(cc, bb,  f2);
                }
            }
        }
        // CNOT ring (0,1),(1,2),(2,3),(3,0): register renames, free
#pragma unroll
        for (int q = 0; q < 4; ++q) {
            const int mc = 8 >> q;
            const int mt = 8 >> ((q + 1) & 3);
#pragma unroll
            for (int x = 0; x < 16; ++x) {
                if ((x & mc) && !(x & mt)) {
                    const float tmp = st[x];
                    st[x]      = st[x | mt];
                    st[x | mt] = tmp;
                }
            }
        }
    }

    // ---- expvals via Walsh tree ----
    float pr[16];
#pragma unroll
    for (int x = 0; x < 16; ++x) pr[x] = st[x] * st[x];

    float a_[8], bd[8];
#pragma unroll
    for (int x = 0; x < 8; ++x) {
        a_[x] = pr[2 * x] + pr[2 * x + 1];
        bd[x] = pr[2 * x] - pr[2 * x + 1];
    }
    const float e3 = ((bd[0] + bd[1]) + (bd[2] + bd[3])) + ((bd[4] + bd[5]) + (bd[6] + bd[7]));
    float c_[4], d_[4];
#pragma unroll
    for (int x = 0; x < 4; ++x) {
        c_[x] = a_[2 * x] + a_[2 * x + 1];
        d_[x] = a_[2 * x] - a_[2 * x + 1];
    }
    const float e2 = (d_[0] + d_[1]) + (d_[2] + d_[3]);
    const float e1 = (c_[0] - c_[1]) + (c_[2] - c_[3]);
    const float e0 = (c_[0] + c_[1]) - (c_[2] + c_[3]);

    *reinterpret_cast<float4*>(out + (((size_t)b * HO + i) * WO + j) * 4) =
        make_float4(e0, e1, e2, e3);
}

extern "C" void kernel_launch(void* const* d_in, const int* in_sizes, int n_in,
                              void* d_out, int out_size, void* d_ws, size_t ws_size,
                              hipStream_t stream) {
    const float* img = (const float*)d_in[0];
    const float* wts = (const float*)d_in[1];
    float* out = (float*)d_out;

    const int B = in_sizes[0] / (H * W);   // 64
    dim3 grid(1, 64, B);                   // 2 rows per block
    dim3 block(256, 1, 1);
    quonv_kernel<<<grid, block, 0, stream>>>(img, wts, out);
}

// Round 4
// 13.545 us; speedup vs baseline: 1.5887x; 1.2406x over previous
//
#include <hip/hip_runtime.h>
#include <hip/hip_bf16.h>

#define H  128
#define W  128
#define HO 127
#define WO 127

// One patch per thread. Block 256 = 128 cols x 2 rows. Grid (1, 64, B).
// Layer-0 RYs are fused into the angle embedding (RY angles add on |0>):
//   product state built from angles  pi*p_w/2 + w0_w/2  directly.
// All sin/cos via raw v_sin_f32/v_cos_f32 (args in revolutions, pre-reduced).
__global__ __launch_bounds__(256) void quonv_kernel(
    const float* __restrict__ img,   // [B,128,128,1]
    const float* __restrict__ wts,   // [2,4] in [0, 2pi]
    float* __restrict__ out)         // [B,127,127,4]
{
    const int t  = threadIdx.x;
    const int j  = t & 127;
    const int ty = t >> 7;
    const int i  = blockIdx.y * 2 + ty;
    const int b  = blockIdx.z;
    if (i >= HO || j >= WO) return;

    const float inv4pi = 0.07957747154594767f;  // 1/(4*pi): rad -> half-angle revolutions

    // ---- layer-1 weight half-angle sincos (independent of loads; issue first) ----
    float wc1[4], ws1[4];
#pragma unroll
    for (int k = 0; k < 4; ++k) {
        const float a = wts[4 + k] * inv4pi;
        wc1[k] = __builtin_amdgcn_cosf(a);
        ws1[k] = __builtin_amdgcn_sinf(a);
    }

    // ---- load 2x2 patch ----
    const float* r0p = img + ((size_t)b * H + i) * W + j;
    float p[4];
    p[0] = r0p[0];
    p[1] = r0p[1];
    p[2] = r0p[W];
    p[3] = r0p[W + 1];

    // ---- fused embedding + layer-0 RY: angle = pi*p_w + w0_w  (rev: p/4 + w0/(4pi)) ----
    float ec[4], es[4];
#pragma unroll
    for (int w = 0; w < 4; ++w) {
        const float a = __builtin_fmaf(p[w], 0.25f, wts[w] * inv4pi);
        ec[w] = __builtin_amdgcn_cosf(a);
        es[w] = __builtin_amdgcn_sinf(a);
    }

    // ---- product state; bit of wire w is bit (3-w) of idx ----
    float t01[4], t23[4];
    t01[0] = ec[0] * ec[1]; t01[1] = ec[0] * es[1];
    t01[2] = es[0] * ec[1]; t01[3] = es[0] * es[1];
    t23[0] = ec[2] * ec[3]; t23[1] = ec[2] * es[3];
    t23[2] = es[2] * ec[3]; t23[3] = es[2] * es[3];

    float st[16];
#pragma unroll
    for (int x = 0; x < 16; ++x)
        st[x] = t01[x >> 2] * t23[x & 3];

    // ---- CNOT ring #1 (register renames, free) ----
#pragma unroll
    for (int q = 0; q < 4; ++q) {
        const int mc = 8 >> q;
        const int mt = 8 >> ((q + 1) & 3);
#pragma unroll
        for (int x = 0; x < 16; ++x) {
            if ((x & mc) && !(x & mt)) {
                const float tmp = st[x];
                st[x]      = st[x | mt];
                st[x | mt] = tmp;
            }
        }
    }

    // ---- layer-1 RYs ----
#pragma unroll
    for (int w = 0; w < 4; ++w) {
        const float cc = wc1[w];
        const float ss = ws1[w];
        const int m = 8 >> w;
#pragma unroll
        for (int x = 0; x < 16; ++x) {
            if (!(x & m)) {
                const float a  = st[x];
                const float bb = st[x | m];
                const float f1 = ss * bb;
                const float f2 = ss * a;
                st[x]     = __builtin_fmaf(cc, a,  -f1);
                st[x | m] = __builtin_fmaf(cc, bb,  f2);
            }
        }
    }

    // ---- CNOT ring #2 (free) ----
#pragma unroll
    for (int q = 0; q < 4; ++q) {
        const int mc = 8 >> q;
        const int mt = 8 >> ((q + 1) & 3);
#pragma unroll
        for (int x = 0; x < 16; ++x) {
            if ((x & mc) && !(x & mt)) {
                const float tmp = st[x];
                st[x]      = st[x | mt];
                st[x | mt] = tmp;
            }
        }
    }

    // ---- expvals via Walsh tree ----
    float pr[16];
#pragma unroll
    for (int x = 0; x < 16; ++x) pr[x] = st[x] * st[x];

    float a_[8], bd[8];
#pragma unroll
    for (int x = 0; x < 8; ++x) {
        a_[x] = pr[2 * x] + pr[2 * x + 1];
        bd[x] = pr[2 * x] - pr[2 * x + 1];
    }
    const float e3 = ((bd[0] + bd[1]) + (bd[2] + bd[3])) + ((bd[4] + bd[5]) + (bd[6] + bd[7]));
    float c_[4], d_[4];
#pragma unroll
    for (int x = 0; x < 4; ++x) {
        c_[x] = a_[2 * x] + a_[2 * x + 1];
        d_[x] = a_[2 * x] - a_[2 * x + 1];
    }
    const float e2 = (d_[0] + d_[1]) + (d_[2] + d_[3]);
    const float e1 = (c_[0] - c_[1]) + (c_[2] - c_[3]);
    const float e0 = (c_[0] + c_[1]) - (c_[2] + c_[3]);

    *reinterpret_cast<float4*>(out + (((size_t)b * HO + i) * WO + j) * 4) =
        make_float4(e0, e1, e2, e3);
}

extern "C" void kernel_launch(void* const* d_in, const int* in_sizes, int n_in,
                              void* d_out, int out_size, void* d_ws, size_t ws_size,
                              hipStream_t stream) {
    const float* img = (const float*)d_in[0];
    const float* wts = (const float*)d_in[1];
    float* out = (float*)d_out;

    const int B = in_sizes[0] / (H * W);   // 64
    dim3 grid(1, 64, B);                   // 2 rows per block
    dim3 block(256, 1, 1);
    quonv_kernel<<<grid, block, 0, stream>>>(img, wts, out);
}

// Round 5
// 11.426 us; speedup vs baseline: 1.8833x; 1.1855x over previous
//
#include <hip/hip_runtime.h>
#include <hip/hip_bf16.h>

#define H  128
#define W  128
#define HO 127
#define WO 127

// Closed-form quanvolution: Heisenberg expansion of O_w = U^T Z_w U in Pauli
// strings. Input product state per wire v: x_v = sin(alpha_v), z_v = cos(alpha_v),
// alpha_v = pi*p_v + theta0_v (layer-0 RY fused into embedding).
// With c_v = cos(theta1_v), s_v = sin(theta1_v) (layer-1, FULL angles):
//   E0 = c1c2c3*z0z1z3 - c1c2s3*x0x1z2x3 - s1c2c3*x1x2z3 - s1s2s3*x0
//   E1 = c0c1*z0z2z3 + s0s1*x0x2
//   E2 = c0c1c2*z1z3 - c0s1c2*z0x1x2z3 - s0c1c2*x0x1z2 - s0s1s2*x0x3
//   E3 = c0c1c2c3*z0z2 - c0c1s2c3*z1x2x3 + s0s1c2c3*x0x2z3 + s0c1c2s3*z2x3
//      + c0s1s2c3*z0x1x3 - s0c1s2s3*z0z1x2 - c0s1s2s3*x0z1z2z3 + s0s1s2s3*x1
// (verified vs hand-simulated circuit on 6 basis/superposition cases)
__global__ __launch_bounds__(256) void quonv_kernel(
    const float* __restrict__ img,   // [B,128,128,1]
    const float* __restrict__ wts,   // [2,4] in [0, 2pi]
    float* __restrict__ out)         // [B,127,127,4]
{
    const int t  = threadIdx.x;
    const int j  = t & 127;
    const int ty = t >> 7;
    const int i  = blockIdx.y * 2 + ty;
    const int b  = blockIdx.z;
    if (i >= HO || j >= WO) return;

    const float inv2pi = 0.15915494309189535f;  // rad -> revolutions

    // ---- layer-1 full-angle sincos (wave-uniform; trans overlaps loads) ----
    float cw[4], sw[4];
#pragma unroll
    for (int k = 0; k < 4; ++k) {
        const float a = wts[4 + k] * inv2pi;
        cw[k] = __builtin_amdgcn_cosf(a);
        sw[k] = __builtin_amdgcn_sinf(a);
    }

    // ---- load 2x2 patch: wire0=r0[j], wire1=r0[j+1], wire2=r1[j], wire3=r1[j+1] ----
    const float* r0p = img + ((size_t)b * H + i) * W + j;
    float p[4];
    p[0] = r0p[0];
    p[1] = r0p[1];
    p[2] = r0p[W];
    p[3] = r0p[W + 1];

    // ---- per-wire Bloch: alpha = pi*p + theta0 -> rev = p/2 + theta0/(2pi) ----
    float xv[4], zv[4];
#pragma unroll
    for (int w = 0; w < 4; ++w) {
        const float a = __builtin_fmaf(p[w], 0.5f, wts[w] * inv2pi);
        xv[w] = __builtin_amdgcn_sinf(a);
        zv[w] = __builtin_amdgcn_cosf(a);
    }

    // ---- weight pair products ----
    const float a_ = cw[0] * cw[1];   // c0c1
    const float b_ = cw[0] * sw[1];   // c0s1
    const float d_ = sw[0] * cw[1];   // s0c1
    const float e_ = sw[0] * sw[1];   // s0s1
    const float f_ = cw[2] * cw[3];   // c2c3
    const float g_ = cw[2] * sw[3];   // c2s3
    const float h_ = sw[2] * cw[3];   // s2c3
    const float k_ = sw[2] * sw[3];   // s2s3

    // ---- shared monomials ----
    const float z2z3 = zv[2] * zv[3];
    const float z0z1 = zv[0] * zv[1];
    const float x0x1 = xv[0] * xv[1];
    const float x1x2 = xv[1] * xv[2];
    const float x0x2 = xv[0] * xv[2];
    const float x2x3 = xv[2] * xv[3];

    // ---- E0 ----
    const float e0 = (cw[1] * f_) * (z0z1 * zv[3])
                   - (cw[1] * g_) * (x0x1 * (zv[2] * xv[3]))
                   - (sw[1] * f_) * (x1x2 * zv[3])
                   - (sw[1] * k_) * xv[0];

    // ---- E1 ----
    const float e1 = a_ * (zv[0] * z2z3) + e_ * x0x2;

    // ---- E2 ----
    const float e2 = (a_ * cw[2]) * (zv[1] * zv[3])
                   - (b_ * cw[2]) * (x1x2 * (zv[0] * zv[3]))
                   - (d_ * cw[2]) * (x0x1 * zv[2])
                   - (e_ * sw[2]) * (xv[0] * xv[3]);

    // ---- E3 ----
    const float e3 = (a_ * f_) * (zv[0] * zv[2])
                   - (a_ * h_) * (zv[1] * x2x3)
                   + (e_ * f_) * (x0x2 * zv[3])
                   + (d_ * g_) * (zv[2] * xv[3])
                   + (b_ * h_) * (zv[0] * (xv[1] * xv[3]))
                   - (d_ * k_) * (z0z1 * xv[2])
                   - (b_ * k_) * (xv[0] * (z2z3 * zv[1]))
                   + (e_ * k_) * xv[1];

    *reinterpret_cast<float4*>(out + (((size_t)b * HO + i) * WO + j) * 4) =
        make_float4(e0, e1, e2, e3);
}

extern "C" void kernel_launch(void* const* d_in, const int* in_sizes, int n_in,
                              void* d_out, int out_size, void* d_ws, size_t ws_size,
                              hipStream_t stream) {
    const float* img = (const float*)d_in[0];
    const float* wts = (const float*)d_in[1];
    float* out = (float*)d_out;

    const int B = in_sizes[0] / (H * W);   // 64
    dim3 grid(1, 64, B);                   // 2 rows per block
    dim3 block(256, 1, 1);
    quonv_kernel<<<grid, block, 0, stream>>>(img, wts, out);
}